// Round 1
// baseline (4614.585 us; speedup 1.0000x reference)
//
#include <hip/hip_runtime.h>
#include <math.h>

#define D_MODEL 256
#define NHEAD 4
#define HEAD_DIM 64
#define SEQ 4096
#define BATCH 4

// ---------------- LayerNorm: one wave per 256-float row ----------------
__global__ __launch_bounds__(256) void ln_kernel(const float* __restrict__ x,
                                                 const float* __restrict__ g,
                                                 const float* __restrict__ b,
                                                 float* __restrict__ o) {
  int lane = threadIdx.x & 63;
  int row = (blockIdx.x << 2) + (threadIdx.x >> 6);
  const float4* xr = (const float4*)(x + (size_t)row * D_MODEL);
  float4 v = xr[lane];
  float s = v.x + v.y + v.z + v.w;
#pragma unroll
  for (int off = 32; off > 0; off >>= 1) s += __shfl_xor(s, off);
  float mu = s * (1.0f / D_MODEL);
  float d0 = v.x - mu, d1 = v.y - mu, d2 = v.z - mu, d3 = v.w - mu;
  float ss = d0 * d0 + d1 * d1 + d2 * d2 + d3 * d3;
#pragma unroll
  for (int off = 32; off > 0; off >>= 1) ss += __shfl_xor(ss, off);
  float r = rsqrtf(ss * (1.0f / D_MODEL) + 1e-5f);
  float4 gv = ((const float4*)g)[lane];
  float4 bv = ((const float4*)b)[lane];
  float4 out;
  out.x = d0 * r * gv.x + bv.x;
  out.y = d1 * r * gv.y + bv.y;
  out.z = d2 * r * gv.z + bv.z;
  out.w = d3 * r * gv.w + bv.w;
  ((float4*)(o + (size_t)row * D_MODEL))[lane] = out;
}

// ---------------- GEMM: C[M,N] = A[M,K] * W[N,K]^T (+bias)(+relu)(+res) ----
// FLAGS: bit0 = bias, bit1 = relu, bit2 = residual add
#define BM 64
#define BN 64
#define BK 32

template <int FLAGS>
__global__ __launch_bounds__(256) void gemm_nt(const float* __restrict__ A,
                                               const float* __restrict__ W,
                                               const float* __restrict__ bias,
                                               const float* __restrict__ res,
                                               float* __restrict__ C, int M,
                                               int N, int K) {
  __shared__ float As[BK][BM + 4];  // k-major (transposed); +4 keeps 16B align
  __shared__ float Ws[BK][BN + 4];
  int t = threadIdx.x;
  int m0 = blockIdx.y * BM, n0 = blockIdx.x * BN;
  int tx = t & 15, ty = t >> 4;  // 16 x 16 threads, 4x4 outputs each
  float acc[4][4] = {};
  int lr = t >> 3;          // row within tile (0..31), +32 on second pass
  int lk = (t & 7) << 2;    // k offset within tile (0,4,...,28)

  for (int k0 = 0; k0 < K; k0 += BK) {
#pragma unroll
    for (int i = 0; i < 2; i++) {
      int r = lr + i * 32;
      float4 av = *(const float4*)(A + (size_t)(m0 + r) * K + k0 + lk);
      As[lk + 0][r] = av.x;
      As[lk + 1][r] = av.y;
      As[lk + 2][r] = av.z;
      As[lk + 3][r] = av.w;
      float4 wv = *(const float4*)(W + (size_t)(n0 + r) * K + k0 + lk);
      Ws[lk + 0][r] = wv.x;
      Ws[lk + 1][r] = wv.y;
      Ws[lk + 2][r] = wv.z;
      Ws[lk + 3][r] = wv.w;
    }
    __syncthreads();
#pragma unroll
    for (int kk = 0; kk < BK; kk++) {
      float4 a = *(const float4*)&As[kk][ty * 4];
      float4 w = *(const float4*)&Ws[kk][tx * 4];
      acc[0][0] += a.x * w.x; acc[0][1] += a.x * w.y; acc[0][2] += a.x * w.z; acc[0][3] += a.x * w.w;
      acc[1][0] += a.y * w.x; acc[1][1] += a.y * w.y; acc[1][2] += a.y * w.z; acc[1][3] += a.y * w.w;
      acc[2][0] += a.z * w.x; acc[2][1] += a.z * w.y; acc[2][2] += a.z * w.z; acc[2][3] += a.z * w.w;
      acc[3][0] += a.w * w.x; acc[3][1] += a.w * w.y; acc[3][2] += a.w * w.z; acc[3][3] += a.w * w.w;
    }
    __syncthreads();
  }

  float4 bv = make_float4(0.f, 0.f, 0.f, 0.f);
  if (FLAGS & 1) bv = *(const float4*)(bias + n0 + tx * 4);
#pragma unroll
  for (int i = 0; i < 4; i++) {
    int m = m0 + ty * 4 + i;
    float4 o;
    o.x = acc[i][0] + bv.x;
    o.y = acc[i][1] + bv.y;
    o.z = acc[i][2] + bv.z;
    o.w = acc[i][3] + bv.w;
    if (FLAGS & 2) {
      o.x = fmaxf(o.x, 0.f); o.y = fmaxf(o.y, 0.f);
      o.z = fmaxf(o.z, 0.f); o.w = fmaxf(o.w, 0.f);
    }
    if (FLAGS & 4) {
      float4 rv = *(const float4*)(res + (size_t)m * N + n0 + tx * 4);
      o.x += rv.x; o.y += rv.y; o.z += rv.z; o.w += rv.w;
    }
    *(float4*)(C + (size_t)m * N + n0 + tx * 4) = o;
  }
}

// ---------------- Causal flash attention, thread-per-query-row -------------
// grid: (SEQ/256, BATCH*NHEAD); block: 256. K/V addresses are wave-uniform
// (blockIdx + loop counters only) -> scalar s_load path; VALU does the FMAs.
__global__ __launch_bounds__(256) void attn_kernel(const float* __restrict__ qg,
                                                   const float* __restrict__ kg,
                                                   const float* __restrict__ vg,
                                                   const float* __restrict__ x,
                                                   float* __restrict__ xt) {
  const int S = SEQ;
  int bh = blockIdx.y;
  int b = bh >> 2;   // / NHEAD
  int h = bh & 3;    // % NHEAD
  int qrow = blockIdx.x * 256 + threadIdx.x;
  size_t base = ((size_t)b * S) * D_MODEL + h * HEAD_DIM;

  // Q row into registers, pre-scaled by 1/TEMP (TEMP = sqrt(64) = 8)
  const float* Qp = qg + base + (size_t)qrow * D_MODEL;
  float4 qr[16];
#pragma unroll
  for (int i = 0; i < 16; i++) {
    float4 t = *(const float4*)(Qp + i * 4);
    t.x *= 0.125f; t.y *= 0.125f; t.z *= 0.125f; t.w *= 0.125f;
    qr[i] = t;
  }

  float4 acc[16];
#pragma unroll
  for (int i = 0; i < 16; i++) acc[i] = make_float4(0.f, 0.f, 0.f, 0.f);
  float m = -1e30f, l = 0.f;

  const float* Kb = kg + base;
  const float* Vb = vg + base;
  int jmax = blockIdx.x * 256 + 255;  // block-uniform causal bound

  for (int j0 = 0; j0 <= jmax; j0 += 8) {
    float s[8] = {0.f, 0.f, 0.f, 0.f, 0.f, 0.f, 0.f, 0.f};
#pragma unroll
    for (int d4 = 0; d4 < 16; d4++) {
      float4 qv = qr[d4];
#pragma unroll
      for (int jj = 0; jj < 8; jj++) {
        float4 kv = *(const float4*)(Kb + (size_t)(j0 + jj) * D_MODEL + d4 * 4);
        s[jj] += qv.x * kv.x + qv.y * kv.y + qv.z * kv.z + qv.w * kv.w;
      }
    }
    // causal mask (per-lane), sentinel avoids inf-inf NaN
#pragma unroll
    for (int jj = 0; jj < 8; jj++)
      if (j0 + jj > qrow) s[jj] = -1e30f;

    float cm = fmaxf(fmaxf(fmaxf(s[0], s[1]), fmaxf(s[2], s[3])),
                     fmaxf(fmaxf(s[4], s[5]), fmaxf(s[6], s[7])));
    float mn = fmaxf(m, cm);
    float alpha = __expf(m - mn);
    float p[8];
    float ps = 0.f;
#pragma unroll
    for (int jj = 0; jj < 8; jj++) {
      p[jj] = __expf(s[jj] - mn);
      ps += p[jj];
    }
    l = l * alpha + ps;
    m = mn;
#pragma unroll
    for (int d4 = 0; d4 < 16; d4++) {
      float4 a = acc[d4];
      a.x *= alpha; a.y *= alpha; a.z *= alpha; a.w *= alpha;
#pragma unroll
      for (int jj = 0; jj < 8; jj++) {
        float4 vv = *(const float4*)(Vb + (size_t)(j0 + jj) * D_MODEL + d4 * 4);
        a.x += p[jj] * vv.x;
        a.y += p[jj] * vv.y;
        a.z += p[jj] * vv.z;
        a.w += p[jj] * vv.w;
      }
      acc[d4] = a;
    }
  }

  // xt = x + attn_out (this block owns dims [h*64, h*64+64) of the row)
  float inv = 1.0f / l;
  const float* xr = x + base + (size_t)qrow * D_MODEL;
  float* xo = xt + base + (size_t)qrow * D_MODEL;
#pragma unroll
  for (int d4 = 0; d4 < 16; d4++) {
    float4 xv = *(const float4*)(xr + d4 * 4);
    float4 o;
    o.x = xv.x + acc[d4].x * inv;
    o.y = xv.y + acc[d4].y * inv;
    o.z = xv.z + acc[d4].z * inv;
    o.w = xv.w + acc[d4].w * inv;
    *(float4*)(xo + d4 * 4) = o;
  }
}

// ---------------------------------------------------------------------------
extern "C" void kernel_launch(void* const* d_in, const int* in_sizes, int n_in,
                              void* d_out, int out_size, void* d_ws,
                              size_t ws_size, hipStream_t stream) {
  const float* x = (const float*)d_in[0];
  const float* Wq = (const float*)d_in[1];
  const float* Wk = (const float*)d_in[2];
  const float* Wv = (const float*)d_in[3];
  const float* g1 = (const float*)d_in[4];
  const float* b1 = (const float*)d_in[5];
  const float* g2 = (const float*)d_in[6];
  const float* b2 = (const float*)d_in[7];
  const float* W1 = (const float*)d_in[8];
  const float* bf1 = (const float*)d_in[9];
  const float* W2 = (const float*)d_in[10];
  const float* bf2 = (const float*)d_in[11];
  float* out = (float*)d_out;

  const int M = BATCH * SEQ;           // 16384
  const size_t n = (size_t)M * D_MODEL;  // 4,194,304 floats per buffer

  float* ws = (float*)d_ws;
  float* xn = ws;            // slot 0 (later reused as xt)
  float* qb = ws + n;        // slot 1 (later reused as h)
  float* kb = ws + 2 * n;    // slot 2 (later reused as f1)
  float* vb = ws + 3 * n;    // slot 3
  float* xt = ws;            // reuse slot 0 (xn dead after QKV)
  float* hb = ws + n;        // reuse slot 1 (q dead after attention)
  float* f1 = ws + 2 * n;    // reuse slot 2 (k dead after attention)

  dim3 lnGrid(M / 4), lnBlk(256);
  dim3 gGrid(D_MODEL / BN, M / BM), gBlk(256);
  dim3 aGrid(SEQ / 256, BATCH * NHEAD), aBlk(256);

  // 1) xn = LN(x, g1, b1)
  ln_kernel<<<lnGrid, lnBlk, 0, stream>>>(x, g1, b1, xn);
  // 2) q/k/v projections
  gemm_nt<0><<<gGrid, gBlk, 0, stream>>>(xn, Wq, nullptr, nullptr, qb, M, D_MODEL, D_MODEL);
  gemm_nt<0><<<gGrid, gBlk, 0, stream>>>(xn, Wk, nullptr, nullptr, kb, M, D_MODEL, D_MODEL);
  gemm_nt<0><<<gGrid, gBlk, 0, stream>>>(xn, Wv, nullptr, nullptr, vb, M, D_MODEL, D_MODEL);
  // 3) xt = x + causal_attention(q,k,v)
  attn_kernel<<<aGrid, aBlk, 0, stream>>>(qb, kb, vb, x, xt);
  // 4) h = LN(xt, g2, b2)
  ln_kernel<<<lnGrid, lnBlk, 0, stream>>>(xt, g2, b2, hb);
  // 5) f1 = relu(h @ W1^T + bf1)
  gemm_nt<3><<<gGrid, gBlk, 0, stream>>>(hb, W1, bf1, nullptr, f1, M, D_MODEL, D_MODEL);
  // 6) out = xt + (f1 @ W2^T + bf2)
  gemm_nt<5><<<gGrid, gBlk, 0, stream>>>(f1, W2, bf2, xt, out, M, D_MODEL, D_MODEL);
}

// Round 2
// 515.392 us; speedup vs baseline: 8.9535x; 8.9535x over previous
//
#include <hip/hip_runtime.h>
#include <math.h>

#define D_MODEL 256
#define NHEAD 4
#define HEAD_DIM 64
#define SEQ 4096
#define BATCH 4

typedef __attribute__((ext_vector_type(8))) short short8;
typedef __attribute__((ext_vector_type(8))) __bf16 bf16x8;
typedef __attribute__((ext_vector_type(4))) float f32x4;

__device__ inline short f2bf(float f) {
  unsigned u = __float_as_uint(f);
  u += 0x7fffu + ((u >> 16) & 1u);
  return (short)(u >> 16);
}

__device__ inline bf16x8 as_bf8(short8 s) {
  union { short8 s; bf16x8 b; } u;
  u.s = s;
  return u.b;
}

// ---------------- LayerNorm: one wave per 256-float row ----------------
__global__ __launch_bounds__(256) void ln_kernel(const float* __restrict__ x,
                                                 const float* __restrict__ g,
                                                 const float* __restrict__ b,
                                                 float* __restrict__ o) {
  int lane = threadIdx.x & 63;
  int row = (blockIdx.x << 2) + (threadIdx.x >> 6);
  const float4* xr = (const float4*)(x + (size_t)row * D_MODEL);
  float4 v = xr[lane];
  float s = v.x + v.y + v.z + v.w;
#pragma unroll
  for (int off = 32; off > 0; off >>= 1) s += __shfl_xor(s, off);
  float mu = s * (1.0f / D_MODEL);
  float d0 = v.x - mu, d1 = v.y - mu, d2 = v.z - mu, d3 = v.w - mu;
  float ss = d0 * d0 + d1 * d1 + d2 * d2 + d3 * d3;
#pragma unroll
  for (int off = 32; off > 0; off >>= 1) ss += __shfl_xor(ss, off);
  float r = rsqrtf(ss * (1.0f / D_MODEL) + 1e-5f);
  float4 gv = ((const float4*)g)[lane];
  float4 bv = ((const float4*)b)[lane];
  float4 out;
  out.x = d0 * r * gv.x + bv.x;
  out.y = d1 * r * gv.y + bv.y;
  out.z = d2 * r * gv.z + bv.z;
  out.w = d3 * r * gv.w + bv.w;
  ((float4*)(o + (size_t)row * D_MODEL))[lane] = out;
}

// ---------------- GEMM: C[M,N] = A[M,K] * W[N,K]^T (+bias)(+relu)(+res) ----
#define BM 64
#define BN 64
#define BK 32

template <int FLAGS>
__global__ __launch_bounds__(256) void gemm_nt(const float* __restrict__ A,
                                               const float* __restrict__ W,
                                               const float* __restrict__ bias,
                                               const float* __restrict__ res,
                                               float* __restrict__ C, int M,
                                               int N, int K) {
  __shared__ float As[BK][BM + 4];
  __shared__ float Ws[BK][BN + 4];
  int t = threadIdx.x;
  int m0 = blockIdx.y * BM, n0 = blockIdx.x * BN;
  int tx = t & 15, ty = t >> 4;
  float acc[4][4] = {};
  int lr = t >> 3;
  int lk = (t & 7) << 2;

  for (int k0 = 0; k0 < K; k0 += BK) {
#pragma unroll
    for (int i = 0; i < 2; i++) {
      int r = lr + i * 32;
      float4 av = *(const float4*)(A + (size_t)(m0 + r) * K + k0 + lk);
      As[lk + 0][r] = av.x;
      As[lk + 1][r] = av.y;
      As[lk + 2][r] = av.z;
      As[lk + 3][r] = av.w;
      float4 wv = *(const float4*)(W + (size_t)(n0 + r) * K + k0 + lk);
      Ws[lk + 0][r] = wv.x;
      Ws[lk + 1][r] = wv.y;
      Ws[lk + 2][r] = wv.z;
      Ws[lk + 3][r] = wv.w;
    }
    __syncthreads();
#pragma unroll
    for (int kk = 0; kk < BK; kk++) {
      float4 a = *(const float4*)&As[kk][ty * 4];
      float4 w = *(const float4*)&Ws[kk][tx * 4];
      acc[0][0] += a.x * w.x; acc[0][1] += a.x * w.y; acc[0][2] += a.x * w.z; acc[0][3] += a.x * w.w;
      acc[1][0] += a.y * w.x; acc[1][1] += a.y * w.y; acc[1][2] += a.y * w.z; acc[1][3] += a.y * w.w;
      acc[2][0] += a.z * w.x; acc[2][1] += a.z * w.y; acc[2][2] += a.z * w.z; acc[2][3] += a.z * w.w;
      acc[3][0] += a.w * w.x; acc[3][1] += a.w * w.y; acc[3][2] += a.w * w.z; acc[3][3] += a.w * w.w;
    }
    __syncthreads();
  }

  float4 bv = make_float4(0.f, 0.f, 0.f, 0.f);
  if (FLAGS & 1) bv = *(const float4*)(bias + n0 + tx * 4);
#pragma unroll
  for (int i = 0; i < 4; i++) {
    int m = m0 + ty * 4 + i;
    float4 o;
    o.x = acc[i][0] + bv.x;
    o.y = acc[i][1] + bv.y;
    o.z = acc[i][2] + bv.z;
    o.w = acc[i][3] + bv.w;
    if (FLAGS & 2) {
      o.x = fmaxf(o.x, 0.f); o.y = fmaxf(o.y, 0.f);
      o.z = fmaxf(o.z, 0.f); o.w = fmaxf(o.w, 0.f);
    }
    if (FLAGS & 4) {
      float4 rv = *(const float4*)(res + (size_t)m * N + n0 + tx * 4);
      o.x += rv.x; o.y += rv.y; o.z += rv.z; o.w += rv.w;
    }
    *(float4*)(C + (size_t)m * N + n0 + tx * 4) = o;
  }
}

// ---------------- MFMA flash attention (bf16 operands, fp32 softmax/accum) --
// grid: (SEQ/64, BATCH*NHEAD), block 256 (4 waves). Each wave owns 16 q-rows.
// K/V staged per 64-key chunk into LDS in MFMA-fragment order so every
// operand read is one contiguous ds_read_b128 per lane (no bank conflicts).
// Scores in C-layout (col=lane&15=key, row=(lane>>4)*4+r=query [m89]);
// P round-trips through per-wave LDS into A-layout [m120].
__global__ __launch_bounds__(256) void attn_mfma(const float* __restrict__ qg,
                                                 const float* __restrict__ kg,
                                                 const float* __restrict__ vg,
                                                 const float* __restrict__ x,
                                                 float* __restrict__ xt) {
  __shared__ __align__(16) short Qs[64 * 64];      // row-major [q][d], scaled
  __shared__ __align__(16) short Ks[8 * 512];      // B-frag blocks (c*2+fi)
  __shared__ __align__(16) short Vs[8 * 528];      // B-frag blocks (nd*2+fi), padded step
  __shared__ __align__(16) short Ps[4][1024];      // per-wave A-frag P buffer

  const int t = threadIdx.x;
  const int lane = t & 63;
  const int w = t >> 6;
  const int qt = blockIdx.x;
  const int bh = blockIdx.y;
  const int b = bh >> 2, h = bh & 3;
  const int q0 = qt * 64;
  const size_t hbase = (size_t)b * SEQ * D_MODEL + (size_t)h * HEAD_DIM;

  // ---- stage Q tile (pre-scaled by 1/TEMP = 0.125), row-major bf16 ----
  {
    int r = t >> 2;          // local q row 0..63
    int g = t & 3;           // dim group 16g..16g+15
    const float* src = qg + hbase + (size_t)(q0 + r) * D_MODEL + g * 16;
    union { short s[16]; short8 v[2]; } u;
#pragma unroll
    for (int i = 0; i < 16; i += 4) {
      float4 f = *(const float4*)(src + i);
      u.s[i + 0] = f2bf(f.x * 0.125f);
      u.s[i + 1] = f2bf(f.y * 0.125f);
      u.s[i + 2] = f2bf(f.z * 0.125f);
      u.s[i + 3] = f2bf(f.w * 0.125f);
    }
    short8* dst = (short8*)&Qs[r * 64 + g * 16];
    dst[0] = u.v[0];
    dst[1] = u.v[1];
  }
  __syncthreads();

  // Q A-frags for this wave (rows 16w+(lane&15)), k-halves fi=0,1
  bf16x8 qfrag[2];
  {
    int qr = 16 * w + (lane & 15);
#pragma unroll
    for (int fi = 0; fi < 2; fi++)
      qfrag[fi] = as_bf8(*(short8*)&Qs[qr * 64 + fi * 32 + (lane >> 4) * 8]);
  }

  f32x4 oacc[4];
#pragma unroll
  for (int nd = 0; nd < 4; nd++) oacc[nd] = (f32x4){0.f, 0.f, 0.f, 0.f};
  float mrow[4] = {-1e30f, -1e30f, -1e30f, -1e30f};
  float lrow[4] = {0.f, 0.f, 0.f, 0.f};

  const int wq_lo = q0 + 16 * w;   // wave's lowest q row
  const int wq_hi = wq_lo + 15;
  const int nchunks = qt + 1;

  for (int c0 = 0; c0 < nchunks; c0++) {
    const int j0 = c0 * 64;

    // ---- stage K and V chunk (rows j0..j0+63) into frag-order LDS ----
    {
      int r = t >> 2;        // local key 0..63
      int g = t & 3;         // dim group 16g..16g+15
      // K: element (key=r, d) -> block (c= r>>4, fi= d>>5), pos = ((d>>3)&3)*128 + (r&15)*8 + (d&7)
      const float* ksrc = kg + hbase + (size_t)(j0 + r) * D_MODEL + g * 16;
      union { short s[16]; short8 v[2]; } uk;
#pragma unroll
      for (int i = 0; i < 16; i += 4) {
        float4 f = *(const float4*)(ksrc + i);
        uk.s[i + 0] = f2bf(f.x);
        uk.s[i + 1] = f2bf(f.y);
        uk.s[i + 2] = f2bf(f.z);
        uk.s[i + 3] = f2bf(f.w);
      }
      int kc = r >> 4, kn = r & 15, kfi = g >> 1;
      *(short8*)&Ks[(kc * 2 + kfi) * 512 + ((2 * g) & 3) * 128 + kn * 8] = uk.v[0];
      *(short8*)&Ks[(kc * 2 + kfi) * 512 + ((2 * g + 1) & 3) * 128 + kn * 8] = uk.v[1];
      // V: element (key=r, d) -> block (nd= d>>4, fi= r>>5), pos = ((r>>3)&3)*128 + (d&15)*8 + (r&7)
      const float* vsrc = vg + hbase + (size_t)(j0 + r) * D_MODEL + g * 16;
      union { short s[16]; short8 v[2]; } uv;
#pragma unroll
      for (int i = 0; i < 16; i += 4) {
        float4 f = *(const float4*)(vsrc + i);
        uv.s[i + 0] = f2bf(f.x);
        uv.s[i + 1] = f2bf(f.y);
        uv.s[i + 2] = f2bf(f.z);
        uv.s[i + 3] = f2bf(f.w);
      }
      int vfi = r >> 5, vkg = (r >> 3) & 3, vj = r & 7;
      short* vbase = &Vs[(g * 2 + vfi) * 528 + vkg * 128 + vj];
#pragma unroll
      for (int i = 0; i < 16; i++) vbase[i * 8] = uv.s[i];
    }
    __syncthreads();

    if (j0 <= wq_hi) {               // wave-uniform causal skip
      // ---- scores: S[16q x 64k] via 8 MFMAs ----
      f32x4 sc[4];
#pragma unroll
      for (int cc = 0; cc < 4; cc++) {
        f32x4 z = (f32x4){0.f, 0.f, 0.f, 0.f};
        z = __builtin_amdgcn_mfma_f32_16x16x32_bf16(
            qfrag[0], as_bf8(*(short8*)&Ks[(cc * 2 + 0) * 512 + lane * 8]), z, 0, 0, 0);
        z = __builtin_amdgcn_mfma_f32_16x16x32_bf16(
            qfrag[1], as_bf8(*(short8*)&Ks[(cc * 2 + 1) * 512 + lane * 8]), z, 0, 0, 0);
        sc[cc] = z;
      }
      // ---- causal mask (diagonal chunks only) ----
      if (j0 + 63 > wq_lo) {
        int qbase = wq_lo + (lane >> 4) * 4;
        int kbase = j0 + (lane & 15);
#pragma unroll
        for (int cc = 0; cc < 4; cc++)
#pragma unroll
          for (int r = 0; r < 4; r++)
            if (kbase + cc * 16 > qbase + r) sc[cc][r] = -1e30f;
      }
      // ---- online softmax (row reductions across 16-lane groups) ----
      float cmax[4], mn[4], alpha[4], psum[4];
#pragma unroll
      for (int r = 0; r < 4; r++)
        cmax[r] = fmaxf(fmaxf(sc[0][r], sc[1][r]), fmaxf(sc[2][r], sc[3][r]));
#pragma unroll
      for (int off = 1; off < 16; off <<= 1)
#pragma unroll
        for (int r = 0; r < 4; r++)
          cmax[r] = fmaxf(cmax[r], __shfl_xor(cmax[r], off));
      float p[4][4];
#pragma unroll
      for (int r = 0; r < 4; r++) {
        mn[r] = fmaxf(mrow[r], cmax[r]);
        alpha[r] = __expf(mrow[r] - mn[r]);
        mrow[r] = mn[r];
        psum[r] = 0.f;
      }
#pragma unroll
      for (int cc = 0; cc < 4; cc++)
#pragma unroll
        for (int r = 0; r < 4; r++) {
          p[cc][r] = __expf(sc[cc][r] - mn[r]);
          psum[r] += p[cc][r];
        }
#pragma unroll
      for (int off = 1; off < 16; off <<= 1)
#pragma unroll
        for (int r = 0; r < 4; r++) psum[r] += __shfl_xor(psum[r], off);
#pragma unroll
      for (int r = 0; r < 4; r++) lrow[r] = lrow[r] * alpha[r] + psum[r];
      // rescale O accumulators
#pragma unroll
      for (int nd = 0; nd < 4; nd++)
#pragma unroll
        for (int r = 0; r < 4; r++) oacc[nd][r] *= alpha[r];
      // ---- P: C-layout regs -> per-wave A-frag LDS buffer ----
      {
        short* pw = &Ps[w][0];
#pragma unroll
        for (int cc = 0; cc < 4; cc++) {
          int blkoff = (cc >> 1) * 512 + ((cc & 1) * 2 + ((lane & 15) >> 3)) * 128 + (lane & 7);
#pragma unroll
          for (int r = 0; r < 4; r++)
            pw[blkoff + ((lane >> 4) * 4 + r) * 8] = f2bf(p[cc][r]);
        }
      }
      // ---- O += P(16x64) * V(64x64): 8 MFMAs ----
#pragma unroll
      for (int nd = 0; nd < 4; nd++) {
        f32x4 o = oacc[nd];
#pragma unroll
        for (int fi = 0; fi < 2; fi++) {
          bf16x8 pf = as_bf8(*(short8*)&Ps[w][fi * 512 + lane * 8]);
          bf16x8 vf = as_bf8(*(short8*)&Vs[(nd * 2 + fi) * 528 + lane * 8]);
          o = __builtin_amdgcn_mfma_f32_16x16x32_bf16(pf, vf, o, 0, 0, 0);
        }
        oacc[nd] = o;
      }
    }
    __syncthreads();  // protect Ks/Vs before next chunk's staging
  }

  // ---- epilogue: xt = x + O / l ----
  {
    int qloc = 16 * w + (lane >> 4) * 4;
    int dcol = lane & 15;
#pragma unroll
    for (int r = 0; r < 4; r++) {
      float invl = 1.0f / lrow[r];
      size_t rowoff = hbase + (size_t)(q0 + qloc + r) * D_MODEL;
#pragma unroll
      for (int nd = 0; nd < 4; nd++) {
        float val = oacc[nd][r] * invl + x[rowoff + nd * 16 + dcol];
        xt[rowoff + nd * 16 + dcol] = val;
      }
    }
  }
}

// ---------------------------------------------------------------------------
extern "C" void kernel_launch(void* const* d_in, const int* in_sizes, int n_in,
                              void* d_out, int out_size, void* d_ws,
                              size_t ws_size, hipStream_t stream) {
  const float* x = (const float*)d_in[0];
  const float* Wq = (const float*)d_in[1];
  const float* Wk = (const float*)d_in[2];
  const float* Wv = (const float*)d_in[3];
  const float* g1 = (const float*)d_in[4];
  const float* b1 = (const float*)d_in[5];
  const float* g2 = (const float*)d_in[6];
  const float* b2 = (const float*)d_in[7];
  const float* W1 = (const float*)d_in[8];
  const float* bf1 = (const float*)d_in[9];
  const float* W2 = (const float*)d_in[10];
  const float* bf2 = (const float*)d_in[11];
  float* out = (float*)d_out;

  const int M = BATCH * SEQ;
  const size_t n = (size_t)M * D_MODEL;

  float* ws = (float*)d_ws;
  float* xn = ws;
  float* qb = ws + n;
  float* kb = ws + 2 * n;
  float* vb = ws + 3 * n;
  float* xt = ws;          // reuse slot 0
  float* hb = ws + n;      // reuse slot 1
  float* f1 = ws + 2 * n;  // reuse slot 2

  dim3 lnGrid(M / 4), lnBlk(256);
  dim3 gGrid(D_MODEL / BN, M / BM), gBlk(256);
  dim3 aGrid(SEQ / 64, BATCH * NHEAD), aBlk(256);

  ln_kernel<<<lnGrid, lnBlk, 0, stream>>>(x, g1, b1, xn);
  gemm_nt<0><<<gGrid, gBlk, 0, stream>>>(xn, Wq, nullptr, nullptr, qb, M, D_MODEL, D_MODEL);
  gemm_nt<0><<<gGrid, gBlk, 0, stream>>>(xn, Wk, nullptr, nullptr, kb, M, D_MODEL, D_MODEL);
  gemm_nt<0><<<gGrid, gBlk, 0, stream>>>(xn, Wv, nullptr, nullptr, vb, M, D_MODEL, D_MODEL);
  attn_mfma<<<aGrid, aBlk, 0, stream>>>(qb, kb, vb, x, xt);
  ln_kernel<<<lnGrid, lnBlk, 0, stream>>>(xt, g2, b2, hb);
  gemm_nt<3><<<gGrid, gBlk, 0, stream>>>(hb, W1, bf1, nullptr, f1, M, D_MODEL, D_MODEL);
  gemm_nt<5><<<gGrid, gBlk, 0, stream>>>(f1, W2, bf2, xt, out, M, D_MODEL, D_MODEL);
}

// Round 3
// 306.441 us; speedup vs baseline: 15.0586x; 1.6819x over previous
//
#include <hip/hip_runtime.h>
#include <math.h>

#define D_MODEL 256
#define NHEAD 4
#define HEAD_DIM 64
#define SEQ 4096
#define BATCH 4
#define MROWS (BATCH * SEQ)

typedef __attribute__((ext_vector_type(8))) short short8;
typedef __attribute__((ext_vector_type(4))) short short4v;
typedef __attribute__((ext_vector_type(8))) __bf16 bf16x8;
typedef __attribute__((ext_vector_type(4))) float f32x4;

__device__ inline short f2bf(float f) {
  unsigned u = __float_as_uint(f);
  u += 0x7fffu + ((u >> 16) & 1u);
  return (short)(u >> 16);
}
__device__ inline bf16x8 as_bf8(short8 s) {
  union { short8 s; bf16x8 b; } u;
  u.s = s;
  return u.b;
}

// ---------------- one-shot weight fp32->bf16 convert (5 x 256x256) --------
__global__ __launch_bounds__(256) void wcvt(const float* __restrict__ s0, const float* __restrict__ s1,
                                            const float* __restrict__ s2, const float* __restrict__ s3,
                                            const float* __restrict__ s4, short* __restrict__ d0,
                                            short* __restrict__ d1, short* __restrict__ d2,
                                            short* __restrict__ d3, short* __restrict__ d4) {
  int mat = blockIdx.x >> 6;
  int idx = ((blockIdx.x & 63) * 256 + threadIdx.x) * 4;
  const float* s = mat == 0 ? s0 : mat == 1 ? s1 : mat == 2 ? s2 : mat == 3 ? s3 : s4;
  short* d = mat == 0 ? d0 : mat == 1 ? d1 : mat == 2 ? d2 : mat == 3 ? d3 : d4;
  float4 f = *(const float4*)(s + idx);
  short4v o = {f2bf(f.x), f2bf(f.y), f2bf(f.z), f2bf(f.w)};
  *(short4v*)(d + idx) = o;
}

// ---------------- LayerNorm fp32 -> bf16, one wave per row -----------------
__global__ __launch_bounds__(256) void ln_bf(const float* __restrict__ x,
                                             const float* __restrict__ g,
                                             const float* __restrict__ b,
                                             short* __restrict__ o) {
  int lane = threadIdx.x & 63;
  int row = (blockIdx.x << 2) + (threadIdx.x >> 6);
  float4 v = ((const float4*)(x + (size_t)row * D_MODEL))[lane];
  float s = v.x + v.y + v.z + v.w;
#pragma unroll
  for (int off = 32; off > 0; off >>= 1) s += __shfl_xor(s, off);
  float mu = s * (1.0f / D_MODEL);
  float d0 = v.x - mu, d1 = v.y - mu, d2 = v.z - mu, d3 = v.w - mu;
  float ss = d0 * d0 + d1 * d1 + d2 * d2 + d3 * d3;
#pragma unroll
  for (int off = 32; off > 0; off >>= 1) ss += __shfl_xor(ss, off);
  float r = rsqrtf(ss * (1.0f / D_MODEL) + 1e-5f);
  float4 gv = ((const float4*)g)[lane];
  float4 bv = ((const float4*)b)[lane];
  short4v out = {f2bf(d0 * r * gv.x + bv.x), f2bf(d1 * r * gv.y + bv.y),
                 f2bf(d2 * r * gv.z + bv.z), f2bf(d3 * r * gv.w + bv.w)};
  *(short4v*)(o + (size_t)row * D_MODEL + lane * 4) = out;
}

// ---------------- bf16 MFMA GEMM, 128x128 tile, fused epilogues ------------
// Wb: [256,256] bf16 (N,K) row-major; Xb: [M,256] bf16 row-major.
// Modes != VT compute D[n][m] (lane&15 = x-row) so each lane packs 4
// consecutive n -> b64 bf16 / float4 stores. VT computes D[m][n] and writes
// V^T [b,h,d,s] directly (lane&15 = feature, 4 consecutive s per reg-quad).
#define GM_Q 0
#define GM_K 1
#define GM_VT 2
#define GM_F1 3
#define GM_OUT 4

template <int MODE>
__global__ __launch_bounds__(256) void gemm_mfma(const short* __restrict__ Wb,
                                                 const short* __restrict__ Xb,
                                                 const float* __restrict__ bias,
                                                 const float* __restrict__ res,
                                                 void* __restrict__ outp) {
  __shared__ __align__(16) short Ws[128 * 32];
  __shared__ __align__(16) short Xs[128 * 32];
  const int t = threadIdx.x, lane = t & 63, w = t >> 6;
  const int wm = w >> 1, wn = w & 1, l15 = lane & 15, quad = lane >> 4;
  const int m0 = blockIdx.x * 128, n0 = blockIdx.y * 128;
  f32x4 acc[4][4];
#pragma unroll
  for (int i = 0; i < 4; i++)
#pragma unroll
    for (int j = 0; j < 4; j++) acc[i][j] = (f32x4){0.f, 0.f, 0.f, 0.f};

  for (int k0 = 0; k0 < D_MODEL; k0 += 32) {
#pragma unroll
    for (int i = 0; i < 2; i++) {
      int cid = i * 256 + t;
      int row = cid >> 2, ch = (cid & 3) * 8;
      *(short8*)&Ws[row * 32 + ch] = *(const short8*)&Wb[(n0 + row) * D_MODEL + k0 + ch];
      *(short8*)&Xs[row * 32 + ch] = *(const short8*)&Xb[(size_t)(m0 + row) * D_MODEL + k0 + ch];
    }
    __syncthreads();
    bf16x8 fw[4], fx[4];
#pragma unroll
    for (int i = 0; i < 4; i++) {
      fw[i] = as_bf8(*(short8*)&Ws[(wn * 64 + i * 16 + l15) * 32 + quad * 8]);
      fx[i] = as_bf8(*(short8*)&Xs[(wm * 64 + i * 16 + l15) * 32 + quad * 8]);
    }
#pragma unroll
    for (int mt = 0; mt < 4; mt++)
#pragma unroll
      for (int nt = 0; nt < 4; nt++) {
        if (MODE == GM_VT)
          acc[mt][nt] = __builtin_amdgcn_mfma_f32_16x16x32_bf16(fx[mt], fw[nt], acc[mt][nt], 0, 0, 0);
        else
          acc[mt][nt] = __builtin_amdgcn_mfma_f32_16x16x32_bf16(fw[nt], fx[mt], acc[mt][nt], 0, 0, 0);
      }
    __syncthreads();
  }

#pragma unroll
  for (int mt = 0; mt < 4; mt++)
#pragma unroll
    for (int nt = 0; nt < 4; nt++) {
      if (MODE == GM_VT) {
        int n = n0 + wn * 64 + nt * 16 + l15;       // feature -> (h,d)
        int mb = m0 + wm * 64 + mt * 16 + quad * 4; // 4 consecutive rows (s)
        int h = n >> 6, d = n & 63, b = mb >> 12, s = mb & 4095;
        f32x4 v = acc[mt][nt];
        short4v o = {f2bf(v[0]), f2bf(v[1]), f2bf(v[2]), f2bf(v[3])};
        *(short4v*)((short*)outp + ((size_t)((b * NHEAD + h) * HEAD_DIM + d)) * SEQ + s) = o;
      } else {
        int m = m0 + wm * 64 + mt * 16 + l15;
        int nb = n0 + wn * 64 + nt * 16 + quad * 4;
        f32x4 v = acc[mt][nt];
        if (MODE == GM_Q) v *= 0.125f;  // fold 1/TEMP into Q
        if (MODE == GM_F1 || MODE == GM_OUT) {
          float4 bv = *(const float4*)(bias + nb);
          v[0] += bv.x; v[1] += bv.y; v[2] += bv.z; v[3] += bv.w;
        }
        if (MODE == GM_F1) {
          v[0] = fmaxf(v[0], 0.f); v[1] = fmaxf(v[1], 0.f);
          v[2] = fmaxf(v[2], 0.f); v[3] = fmaxf(v[3], 0.f);
        }
        if (MODE == GM_OUT) {
          float4 rv = *(const float4*)(res + (size_t)m * D_MODEL + nb);
          float4 o4 = make_float4(v[0] + rv.x, v[1] + rv.y, v[2] + rv.z, v[3] + rv.w);
          *(float4*)((float*)outp + (size_t)m * D_MODEL + nb) = o4;
        } else {
          short4v o = {f2bf(v[0]), f2bf(v[1]), f2bf(v[2]), f2bf(v[3])};
          *(short4v*)((short*)outp + (size_t)m * D_MODEL + nb) = o;
        }
      }
    }
}

// ---------------- MFMA flash attention, transposed formulation -------------
// S^T = K·Q^T, O^T = V^T·P^T. Per-lane softmax state is scalar (q = lane&15).
// K/Vt staged with XOR-swizzled b128 writes -> conflict-free b128 frag reads.
__global__ __launch_bounds__(256) void attn_mfma2(const short* __restrict__ qb,
                                                  const short* __restrict__ kb,
                                                  const short* __restrict__ vt,
                                                  const float* __restrict__ x,
                                                  float* __restrict__ xt) {
  __shared__ __align__(16) short Ks[64 * 64];
  __shared__ __align__(16) short Vts[64 * 64];
  __shared__ __align__(16) short Pt[4][16 * 72];  // per-wave [q][key], padded

  const int t = threadIdx.x, lane = t & 63, w = t >> 6;
  const int quad = lane >> 4, l15 = lane & 15, l7 = lane & 7;
  const int qt = (int)gridDim.x - 1 - (int)blockIdx.x;  // long blocks first
  const int bh = blockIdx.y, b = bh >> 2, h = bh & 3;
  const int q0 = qt * 64;
  const int qrow = q0 + w * 16 + l15;
  const size_t xrowbase = ((size_t)b * SEQ + qrow) * D_MODEL + h * HEAD_DIM;

  bf16x8 qf[2];
  {
    const short* qp = qb + ((size_t)b * SEQ + qrow) * D_MODEL + h * HEAD_DIM + quad * 8;
    qf[0] = as_bf8(*(const short8*)qp);
    qf[1] = as_bf8(*(const short8*)(qp + 32));
  }

  f32x4 oacc[4];
#pragma unroll
  for (int i = 0; i < 4; i++) oacc[i] = (f32x4){0.f, 0.f, 0.f, 0.f};
  float mrun = -1e30f, lrun = 0.f;
  const int wq_hi = q0 + w * 16 + 15;

  const short* kbase = kb + ((size_t)b * SEQ) * D_MODEL + h * HEAD_DIM;
  const short* vbase = vt + ((size_t)(b * NHEAD + h) * HEAD_DIM) * SEQ;

  for (int c0 = 0; c0 <= qt; c0++) {
    const int j0 = c0 * 64;
#pragma unroll
    for (int i = 0; i < 2; i++) {
      int cid = i * 256 + t;
      int r = cid >> 3, ch = cid & 7;
      short8 kv = *(const short8*)(kbase + (size_t)(j0 + r) * D_MODEL + ch * 8);
      *(short8*)&Ks[r * 64 + ((ch ^ (r & 7)) * 8)] = kv;
      short8 vv = *(const short8*)(vbase + (size_t)r * SEQ + j0 + ch * 8);
      *(short8*)&Vts[r * 64 + ((ch ^ (r & 7)) * 8)] = vv;
    }
    __syncthreads();

    if (j0 <= wq_hi) {
      // ---- S^T[key][q]: 8 MFMAs ----
      f32x4 st[4];
#pragma unroll
      for (int kc = 0; kc < 4; kc++) {
        f32x4 z = (f32x4){0.f, 0.f, 0.f, 0.f};
#pragma unroll
        for (int fi = 0; fi < 2; fi++) {
          bf16x8 kf = as_bf8(*(short8*)&Ks[(kc * 16 + l15) * 64 + (((fi * 4 + quad) ^ l7) * 8)]);
          z = __builtin_amdgcn_mfma_f32_16x16x32_bf16(kf, qf[fi], z, 0, 0, 0);
        }
        st[kc] = z;
      }
      // causal mask only on the diagonal chunk
      if (c0 == qt) {
#pragma unroll
        for (int kc = 0; kc < 4; kc++)
#pragma unroll
          for (int r = 0; r < 4; r++)
            if (j0 + kc * 16 + quad * 4 + r > qrow) st[kc][r] = -1e30f;
      }
      // ---- online softmax: scalar state per lane ----
      float smax = -1e30f;
#pragma unroll
      for (int kc = 0; kc < 4; kc++)
#pragma unroll
        for (int r = 0; r < 4; r++) smax = fmaxf(smax, st[kc][r]);
      smax = fmaxf(smax, __shfl_xor(smax, 16));
      smax = fmaxf(smax, __shfl_xor(smax, 32));
      float mn = fmaxf(mrun, smax);
      float alpha = __expf(mrun - mn);
      mrun = mn;
      float psum = 0.f;
      float p[4][4];
#pragma unroll
      for (int kc = 0; kc < 4; kc++)
#pragma unroll
        for (int r = 0; r < 4; r++) {
          p[kc][r] = __expf(st[kc][r] - mn);
          psum += p[kc][r];
        }
      psum += __shfl_xor(psum, 16);
      psum += __shfl_xor(psum, 32);
      lrun = lrun * alpha + psum;
#pragma unroll
      for (int i = 0; i < 4; i++) oacc[i] *= alpha;
      // ---- P^T -> per-wave LDS [q][key], packed b64 writes ----
#pragma unroll
      for (int kc = 0; kc < 4; kc++) {
        short4v pv = {f2bf(p[kc][0]), f2bf(p[kc][1]), f2bf(p[kc][2]), f2bf(p[kc][3])};
        *(short4v*)&Pt[w][l15 * 72 + kc * 16 + quad * 4] = pv;
      }
      // ---- O^T += V^T·P^T: 8 MFMAs ----
#pragma unroll
      for (int dt = 0; dt < 4; dt++) {
        f32x4 o = oacc[dt];
#pragma unroll
        for (int fi = 0; fi < 2; fi++) {
          bf16x8 vf = as_bf8(*(short8*)&Vts[(dt * 16 + l15) * 64 + (((fi * 4 + quad) ^ l7) * 8)]);
          bf16x8 pf = as_bf8(*(short8*)&Pt[w][l15 * 72 + fi * 32 + quad * 8]);
          o = __builtin_amdgcn_mfma_f32_16x16x32_bf16(vf, pf, o, 0, 0, 0);
        }
        oacc[dt] = o;
      }
    }
    __syncthreads();
  }

  // ---- epilogue: xt[q][h*64+d] = x + O^T/l ----
  float inv = 1.0f / lrun;
#pragma unroll
  for (int dt = 0; dt < 4; dt++) {
    size_t addr = xrowbase + dt * 16 + quad * 4;
    float4 xv = *(const float4*)(x + addr);
    float4 o = make_float4(oacc[dt][0] * inv + xv.x, oacc[dt][1] * inv + xv.y,
                           oacc[dt][2] * inv + xv.z, oacc[dt][3] * inv + xv.w);
    *(float4*)(xt + addr) = o;
  }
}

// ---------------------------------------------------------------------------
extern "C" void kernel_launch(void* const* d_in, const int* in_sizes, int n_in,
                              void* d_out, int out_size, void* d_ws,
                              size_t ws_size, hipStream_t stream) {
  const float* x = (const float*)d_in[0];
  const float* Wq = (const float*)d_in[1];
  const float* Wk = (const float*)d_in[2];
  const float* Wv = (const float*)d_in[3];
  const float* g1 = (const float*)d_in[4];
  const float* b1 = (const float*)d_in[5];
  const float* g2 = (const float*)d_in[6];
  const float* b2 = (const float*)d_in[7];
  const float* W1 = (const float*)d_in[8];
  const float* bf1 = (const float*)d_in[9];
  const float* W2 = (const float*)d_in[10];
  const float* bf2 = (const float*)d_in[11];
  float* out = (float*)d_out;

  char* ws = (char*)d_ws;
  float* xt = (float*)ws;                         // 16 MB
  short* q_bf = (short*)(ws + (16u << 20));       // 8 MB
  short* k_bf = (short*)(ws + (24u << 20));       // 8 MB
  short* vt_bf = (short*)(ws + (32u << 20));      // 8 MB
  short* xn_bf = (short*)(ws + (40u << 20));      // 8 MB (also h after attn)
  short* f1_bf = q_bf;                            // q dead after attention
  short* wq_bf = (short*)(ws + (48u << 20));
  short* wk_bf = wq_bf + 65536;
  short* wv_bf = wq_bf + 2 * 65536;
  short* w1_bf = wq_bf + 3 * 65536;
  short* w2_bf = wq_bf + 4 * 65536;

  dim3 gGrid(MROWS / 128, 2), blk(256);
  dim3 lnGrid(MROWS / 4);
  dim3 aGrid(SEQ / 64, BATCH * NHEAD);

  wcvt<<<320, blk, 0, stream>>>(Wq, Wk, Wv, W1, W2, wq_bf, wk_bf, wv_bf, w1_bf, w2_bf);
  ln_bf<<<lnGrid, blk, 0, stream>>>(x, g1, b1, xn_bf);
  gemm_mfma<GM_Q><<<gGrid, blk, 0, stream>>>(wq_bf, xn_bf, nullptr, nullptr, q_bf);
  gemm_mfma<GM_K><<<gGrid, blk, 0, stream>>>(wk_bf, xn_bf, nullptr, nullptr, k_bf);
  gemm_mfma<GM_VT><<<gGrid, blk, 0, stream>>>(wv_bf, xn_bf, nullptr, nullptr, vt_bf);
  attn_mfma2<<<aGrid, blk, 0, stream>>>(q_bf, k_bf, vt_bf, x, xt);
  ln_bf<<<lnGrid, blk, 0, stream>>>(xt, g2, b2, xn_bf);
  gemm_mfma<GM_F1><<<gGrid, blk, 0, stream>>>(w1_bf, xn_bf, bf1, nullptr, f1_bf);
  gemm_mfma<GM_OUT><<<gGrid, blk, 0, stream>>>(w2_bf, f1_bf, bf2, xt, out);
}

// Round 4
// 220.051 us; speedup vs baseline: 20.9705x; 1.3926x over previous
//
#include <hip/hip_runtime.h>
#include <math.h>

#define D_MODEL 256
#define NHEAD 4
#define HEAD_DIM 64
#define SEQ 4096
#define BATCH 4
#define MROWS (BATCH * SEQ)

typedef __attribute__((ext_vector_type(8))) short short8;
typedef __attribute__((ext_vector_type(4))) short short4v;
typedef __attribute__((ext_vector_type(8))) __bf16 bf16x8;
typedef __attribute__((ext_vector_type(4))) float f32x4;

__device__ inline short f2bf(float f) {  // RNE fp32->bf16
  unsigned u = __float_as_uint(f);
  u += 0x7fffu + ((u >> 16) & 1u);
  return (short)(u >> 16);
}
__device__ inline bf16x8 as_bf8(short8 s) {
  union { short8 s; bf16x8 b; } u;
  u.s = s;
  return u.b;
}
// async global->LDS, 16B per lane; LDS dest = wave-uniform base + lane*16
__device__ __forceinline__ void g2lds16(const void* g, void* l) {
  __builtin_amdgcn_global_load_lds(
      (const __attribute__((address_space(1))) unsigned int*)g,
      (__attribute__((address_space(3))) unsigned int*)l, 16, 0, 0);
}

// ---------------- one-shot weight fp32->bf16 convert (5 x 256x256) --------
__global__ __launch_bounds__(256) void wcvt(const float* __restrict__ s0, const float* __restrict__ s1,
                                            const float* __restrict__ s2, const float* __restrict__ s3,
                                            const float* __restrict__ s4, short* __restrict__ d0,
                                            short* __restrict__ d1, short* __restrict__ d2,
                                            short* __restrict__ d3, short* __restrict__ d4) {
  int mat = blockIdx.x >> 6;
  int idx = ((blockIdx.x & 63) * 256 + threadIdx.x) * 4;
  const float* s = mat == 0 ? s0 : mat == 1 ? s1 : mat == 2 ? s2 : mat == 3 ? s3 : s4;
  short* d = mat == 0 ? d0 : mat == 1 ? d1 : mat == 2 ? d2 : mat == 3 ? d3 : d4;
  float4 f = *(const float4*)(s + idx);
  short4v o = {f2bf(f.x), f2bf(f.y), f2bf(f.z), f2bf(f.w)};
  *(short4v*)(d + idx) = o;
}

// ---------------- LayerNorm fp32 -> bf16, one wave per row -----------------
__global__ __launch_bounds__(256) void ln_bf(const float* __restrict__ x,
                                             const float* __restrict__ g,
                                             const float* __restrict__ b,
                                             short* __restrict__ o) {
  int lane = threadIdx.x & 63;
  int row = (blockIdx.x << 2) + (threadIdx.x >> 6);
  float4 v = ((const float4*)(x + (size_t)row * D_MODEL))[lane];
  float s = v.x + v.y + v.z + v.w;
#pragma unroll
  for (int off = 32; off > 0; off >>= 1) s += __shfl_xor(s, off);
  float mu = s * (1.0f / D_MODEL);
  float d0 = v.x - mu, d1 = v.y - mu, d2 = v.z - mu, d3 = v.w - mu;
  float ss = d0 * d0 + d1 * d1 + d2 * d2 + d3 * d3;
#pragma unroll
  for (int off = 32; off > 0; off >>= 1) ss += __shfl_xor(ss, off);
  float r = rsqrtf(ss * (1.0f / D_MODEL) + 1e-5f);
  float4 gv = ((const float4*)g)[lane];
  float4 bv = ((const float4*)b)[lane];
  short4v out = {f2bf(d0 * r * gv.x + bv.x), f2bf(d1 * r * gv.y + bv.y),
                 f2bf(d2 * r * gv.z + bv.z), f2bf(d3 * r * gv.w + bv.w)};
  *(short4v*)(o + (size_t)row * D_MODEL + lane * 4) = out;
}

// ---------------- bf16 MFMA GEMM, 64x64 tile, BK=32, global_load_lds -------
// Modes: GQKV (blockIdx.y selects Q/K/VT, fused), GF1 (bias+relu), GOUT
// (bias+residual, fp32 out). K and VT are written in pre-swizzled
// "attention chunk image" order so attention can DMA them straight to LDS.
#define GQKV 0
#define GF1 1
#define GOUT 2
#define QSCALE 0.1803368801111204f  /* 0.125 * log2(e): exp2-domain scores */

template <int MODE>
__global__ __launch_bounds__(256) void gemm64(const short* __restrict__ W0,
                                              const short* __restrict__ Wk_,
                                              const short* __restrict__ Wv_,
                                              const short* __restrict__ Xb,
                                              const float* __restrict__ bias,
                                              const float* __restrict__ res,
                                              void* __restrict__ o0,
                                              void* __restrict__ o1,
                                              void* __restrict__ o2) {
  __shared__ __align__(16) short Xs[64 * 32];
  __shared__ __align__(16) short Ws[64 * 32];
  const int t = threadIdx.x, lane = t & 63;
  const int l15 = lane & 15, quad = lane >> 4;
  const int wm = (t >> 6) & 1, wn = t >> 7;  // wave quadrant: 32m x 32n
  const int m0 = blockIdx.x * 64;
  int which = 0, n0;
  const short* Wb;
  if (MODE == GQKV) {
    which = blockIdx.y >> 2;
    n0 = (blockIdx.y & 3) * 64;
    Wb = which == 0 ? W0 : which == 1 ? Wk_ : Wv_;
  } else {
    n0 = blockIdx.y * 64;
    Wb = W0;
  }
  const int ldsoff = __builtin_amdgcn_readfirstlane((t >> 6) * 512);
  const int arow = t >> 2, acol = (t & 3) * 8;

  f32x4 acc[2][2];
#pragma unroll
  for (int i = 0; i < 2; i++)
#pragma unroll
    for (int j = 0; j < 2; j++) acc[i][j] = (f32x4){0.f, 0.f, 0.f, 0.f};

  for (int k0 = 0; k0 < D_MODEL; k0 += 32) {
    g2lds16(Xb + (size_t)(m0 + arow) * D_MODEL + k0 + acol, &Xs[ldsoff]);
    g2lds16(Wb + (size_t)(n0 + arow) * D_MODEL + k0 + acol, &Ws[ldsoff]);
    __syncthreads();
    bf16x8 fx[2], fw[2];
#pragma unroll
    for (int i = 0; i < 2; i++) {
      fx[i] = as_bf8(*(short8*)&Xs[(wm * 32 + i * 16 + l15) * 32 + quad * 8]);
      fw[i] = as_bf8(*(short8*)&Ws[(wn * 32 + i * 16 + l15) * 32 + quad * 8]);
    }
#pragma unroll
    for (int mt = 0; mt < 2; mt++)
#pragma unroll
      for (int nt = 0; nt < 2; nt++) {
        if (MODE == GQKV && which == 2)
          acc[mt][nt] = __builtin_amdgcn_mfma_f32_16x16x32_bf16(fx[mt], fw[nt], acc[mt][nt], 0, 0, 0);
        else
          acc[mt][nt] = __builtin_amdgcn_mfma_f32_16x16x32_bf16(fw[nt], fx[mt], acc[mt][nt], 0, 0, 0);
      }
    __syncthreads();
  }

#pragma unroll
  for (int mt = 0; mt < 2; mt++)
#pragma unroll
    for (int nt = 0; nt < 2; nt++) {
      f32x4 v = acc[mt][nt];
      if (MODE == GQKV && which == 2) {
        // VT image: D[m=s][n=feature], rows via quad*4+reg, cols via l15
        int n = n0 + wn * 32 + nt * 16 + l15;
        int mr = m0 + wm * 32 + mt * 16 + quad * 4;
        int b = mr >> 12, s = mr & 4095, h = n >> 6, d = n & 63;
        size_t off = ((size_t)(b * NHEAD + h) * 64 + (s >> 6)) * 4096 +
                     (size_t)d * 64 + ((((s & 63) >> 3) ^ (d & 7)) * 8) + (s & 7);
        short4v o = {f2bf(v[0]), f2bf(v[1]), f2bf(v[2]), f2bf(v[3])};
        *(short4v*)((short*)o2 + off) = o;
      } else {
        int m = m0 + wm * 32 + mt * 16 + l15;
        int nb = n0 + wn * 32 + nt * 16 + quad * 4;
        if (MODE == GQKV) {
          if (which == 0) {  // Q row-major, exp2-domain scale
            v *= QSCALE;
            short4v o = {f2bf(v[0]), f2bf(v[1]), f2bf(v[2]), f2bf(v[3])};
            *(short4v*)((short*)o0 + (size_t)m * D_MODEL + nb) = o;
          } else {  // K image
            int b = m >> 12, s = m & 4095, h = nb >> 6, d = nb & 63;
            size_t off = ((size_t)(b * NHEAD + h) * 64 + (s >> 6)) * 4096 +
                         (size_t)(s & 63) * 64 + (((d >> 3) ^ (s & 7)) * 8) + (d & 7);
            short4v o = {f2bf(v[0]), f2bf(v[1]), f2bf(v[2]), f2bf(v[3])};
            *(short4v*)((short*)o1 + off) = o;
          }
        } else if (MODE == GF1) {
          float4 bv = *(const float4*)(bias + nb);
          short4v o = {f2bf(fmaxf(v[0] + bv.x, 0.f)), f2bf(fmaxf(v[1] + bv.y, 0.f)),
                       f2bf(fmaxf(v[2] + bv.z, 0.f)), f2bf(fmaxf(v[3] + bv.w, 0.f))};
          *(short4v*)((short*)o0 + (size_t)m * D_MODEL + nb) = o;
        } else {  // GOUT
          float4 bv = *(const float4*)(bias + nb);
          float4 rv = *(const float4*)(res + (size_t)m * D_MODEL + nb);
          float4 o4 = make_float4(v[0] + bv.x + rv.x, v[1] + bv.y + rv.y,
                                  v[2] + bv.z + rv.z, v[3] + bv.w + rv.w);
          *(float4*)((float*)o0 + (size_t)m * D_MODEL + nb) = o4;
        }
      }
    }
}

// ---------------- MFMA flash attention v3 ----------------------------------
// grid (32, 16): block = pair of tiles {63-p, p} -> exactly 33 iterations of
// 128 keys each, perfectly balanced. K/Vt DMA'd from pre-swizzled images via
// global_load_lds; S^T = K.Q^T; softmax in exp2 domain (scale folded into Q);
// P^T per-wave in LDS (no barrier); O^T = V^T.P^T.
__global__ __launch_bounds__(256) void attn_v3(const short* __restrict__ qb,
                                               const short* __restrict__ kimg,
                                               const short* __restrict__ vimg,
                                               const float* __restrict__ x,
                                               float* __restrict__ xt) {
  __shared__ __align__(16) short Ks[2 * 4096];
  __shared__ __align__(16) short Vs[2 * 4096];
  __shared__ __align__(16) short Pt[4][16 * 136];  // per-wave [q][key], padded

  const int t = threadIdx.x, lane = t & 63, w = t >> 6;
  const int quad = lane >> 4, l15 = lane & 15;
  const int pair = blockIdx.x;
  const int bh = blockIdx.y, b = bh >> 2, h = bh & 3;
  const int ldsoff = __builtin_amdgcn_readfirstlane(w * 512);
  const short* kb_bh = kimg + (size_t)bh * 64 * 4096;
  const short* vb_bh = vimg + (size_t)bh * 64 * 4096;

  for (int tile = 0; tile < 2; tile++) {
    const int qt = tile == 0 ? 63 - pair : pair;
    const int q0 = qt * 64;
    const int qrow = q0 + w * 16 + l15;
    const int wq_lo = q0 + w * 16, wq_hi = wq_lo + 15;

    bf16x8 qf0, qf1;
    {
      const short* qp = qb + ((size_t)(b * SEQ + qrow)) * D_MODEL + h * HEAD_DIM + quad * 8;
      qf0 = as_bf8(*(const short8*)qp);
      qf1 = as_bf8(*(const short8*)(qp + 32));
    }
    f32x4 oacc[4];
#pragma unroll
    for (int i = 0; i < 4; i++) oacc[i] = (f32x4){0.f, 0.f, 0.f, 0.f};
    float mrun = -1e30f, lrun = 0.f;

    const int niter = (qt + 2) >> 1;
    for (int it = 0; it < niter; it++) {
      const int j0 = it * 128;
      const short* kc_base = kb_bh + (size_t)(2 * it) * 4096;
      const short* vc_base = vb_bh + (size_t)(2 * it) * 4096;
#pragma unroll
      for (int i = 0; i < 4; i++) {
        g2lds16(kc_base + i * 2048 + t * 8, &Ks[i * 2048 + ldsoff]);
        g2lds16(vc_base + i * 2048 + t * 8, &Vs[i * 2048 + ldsoff]);
      }
      __syncthreads();

      const bool half1 = (j0 + 64) <= wq_hi;  // wave-uniform
      const int kcmax = half1 ? 8 : 4;
      f32x4 st[8];
#pragma unroll
      for (int kc = 0; kc < 8; kc++) {
        if (kc < kcmax) {
          int key = kc * 16 + l15;
          int img = (key >> 6) * 4096, r = key & 63;
          f32x4 z = (f32x4){0.f, 0.f, 0.f, 0.f};
          bf16x8 kf0 = as_bf8(*(short8*)&Ks[img + r * 64 + ((quad ^ (r & 7)) * 8)]);
          bf16x8 kf1 = as_bf8(*(short8*)&Ks[img + r * 64 + (((4 + quad) ^ (r & 7)) * 8)]);
          z = __builtin_amdgcn_mfma_f32_16x16x32_bf16(kf0, qf0, z, 0, 0, 0);
          z = __builtin_amdgcn_mfma_f32_16x16x32_bf16(kf1, qf1, z, 0, 0, 0);
          st[kc] = z;
        } else {
          st[kc] = (f32x4){-1e30f, -1e30f, -1e30f, -1e30f};
        }
      }
      // causal mask (only iters overlapping the wave's diagonal)
      if (j0 + 127 > wq_lo) {
#pragma unroll
        for (int kc = 0; kc < 8; kc++)
#pragma unroll
          for (int r = 0; r < 4; r++)
            if (j0 + kc * 16 + quad * 4 + r > qrow) st[kc][r] = -1e30f;
      }
      // online softmax (exp2 domain); state scalar per lane (q = l15)
      float smax = -1e30f;
#pragma unroll
      for (int kc = 0; kc < 8; kc++)
#pragma unroll
        for (int r = 0; r < 4; r++) smax = fmaxf(smax, st[kc][r]);
      smax = fmaxf(smax, __shfl_xor(smax, 16));
      smax = fmaxf(smax, __shfl_xor(smax, 32));
      float mn = fmaxf(mrun, smax);
      float alpha = __builtin_amdgcn_exp2f(mrun - mn);
      mrun = mn;
      float psum = 0.f;
#pragma unroll
      for (int kc = 0; kc < 8; kc++) {
        if (kc < kcmax) {
#pragma unroll
          for (int r = 0; r < 4; r++) {
            float p = __builtin_amdgcn_exp2f(st[kc][r] - mn);
            st[kc][r] = p;
            psum += p;
          }
        }
      }
      psum += __shfl_xor(psum, 16);
      psum += __shfl_xor(psum, 32);
      lrun = lrun * alpha + psum;
#pragma unroll
      for (int i = 0; i < 4; i++) oacc[i] *= alpha;
      // P -> per-wave LDS (bf16 truncation pack, b64 writes; no barrier)
#pragma unroll
      for (int kc = 0; kc < 8; kc++) {
        if (kc < kcmax) {
          unsigned u0 = (__float_as_uint(st[kc][0]) >> 16) | (__float_as_uint(st[kc][1]) & 0xffff0000u);
          unsigned u1 = (__float_as_uint(st[kc][2]) >> 16) | (__float_as_uint(st[kc][3]) & 0xffff0000u);
          uint2 uu = {u0, u1};
          *(uint2*)&Pt[w][l15 * 136 + kc * 16 + quad * 4] = uu;
        }
      }
      const int fimax = half1 ? 4 : 2;
      bf16x8 pf[4];
#pragma unroll
      for (int fi = 0; fi < 4; fi++)
        if (fi < fimax) pf[fi] = as_bf8(*(short8*)&Pt[w][l15 * 136 + fi * 32 + quad * 8]);
#pragma unroll
      for (int dt = 0; dt < 4; dt++) {
        f32x4 o = oacc[dt];
        int d = dt * 16 + l15;
#pragma unroll
        for (int fi = 0; fi < 4; fi++) {
          if (fi < fimax) {
            bf16x8 vf = as_bf8(*(short8*)&Vs[(fi >> 1) * 4096 + d * 64 +
                                             ((((fi & 1) * 4 + quad) ^ (d & 7)) * 8)]);
            o = __builtin_amdgcn_mfma_f32_16x16x32_bf16(vf, pf[fi], o, 0, 0, 0);
          }
        }
        oacc[dt] = o;
      }
      __syncthreads();
    }

    // epilogue: xt[q][h*64 + d] = x + O^T / l   (q = l15, d = dt*16+quad*4+r)
    float inv = 1.0f / lrun;
    size_t rowb = ((size_t)(b * SEQ + qrow)) * D_MODEL + h * HEAD_DIM;
#pragma unroll
    for (int dt = 0; dt < 4; dt++) {
      size_t a = rowb + dt * 16 + quad * 4;
      float4 xv = *(const float4*)(x + a);
      float4 o = make_float4(oacc[dt][0] * inv + xv.x, oacc[dt][1] * inv + xv.y,
                             oacc[dt][2] * inv + xv.z, oacc[dt][3] * inv + xv.w);
      *(float4*)(xt + a) = o;
    }
  }
}

// ---------------------------------------------------------------------------
extern "C" void kernel_launch(void* const* d_in, const int* in_sizes, int n_in,
                              void* d_out, int out_size, void* d_ws,
                              size_t ws_size, hipStream_t stream) {
  const float* x = (const float*)d_in[0];
  const float* Wq = (const float*)d_in[1];
  const float* Wk = (const float*)d_in[2];
  const float* Wv = (const float*)d_in[3];
  const float* g1 = (const float*)d_in[4];
  const float* b1 = (const float*)d_in[5];
  const float* g2 = (const float*)d_in[6];
  const float* b2 = (const float*)d_in[7];
  const float* W1 = (const float*)d_in[8];
  const float* bf1 = (const float*)d_in[9];
  const float* W2 = (const float*)d_in[10];
  const float* bf2 = (const float*)d_in[11];
  float* out = (float*)d_out;

  char* ws = (char*)d_ws;
  float* xt = (float*)ws;                      // 16 MB
  short* q_bf = (short*)(ws + (16u << 20));    // 8 MB
  short* kimg = (short*)(ws + (24u << 20));    // 8 MB (swizzled chunk images)
  short* vimg = (short*)(ws + (32u << 20));    // 8 MB (swizzled chunk images)
  short* xn_bf = (short*)(ws + (40u << 20));   // 8 MB
  short* f1_bf = q_bf;                         // q dead after attention
  short* wq_bf = (short*)(ws + (48u << 20));
  short* wk_bf = wq_bf + 65536;
  short* wv_bf = wq_bf + 2 * 65536;
  short* w1_bf = wq_bf + 3 * 65536;
  short* w2_bf = wq_bf + 4 * 65536;

  dim3 blk(256);
  wcvt<<<320, blk, 0, stream>>>(Wq, Wk, Wv, W1, W2, wq_bf, wk_bf, wv_bf, w1_bf, w2_bf);
  ln_bf<<<MROWS / 4, blk, 0, stream>>>(x, g1, b1, xn_bf);
  gemm64<GQKV><<<dim3(MROWS / 64, 12), blk, 0, stream>>>(
      wq_bf, wk_bf, wv_bf, xn_bf, nullptr, nullptr, q_bf, kimg, vimg);
  attn_v3<<<dim3(32, 16), blk, 0, stream>>>(q_bf, kimg, vimg, x, xt);
  ln_bf<<<MROWS / 4, blk, 0, stream>>>(xt, g2, b2, xn_bf);
  gemm64<GF1><<<dim3(MROWS / 64, 4), blk, 0, stream>>>(
      w1_bf, nullptr, nullptr, xn_bf, bf1, nullptr, f1_bf, nullptr, nullptr);
  gemm64<GOUT><<<dim3(MROWS / 64, 4), blk, 0, stream>>>(
      w2_bf, nullptr, nullptr, f1_bf, bf2, xt, out, nullptr, nullptr);
}